// Round 15
// baseline (107.495 us; speedup 1.0000x reference)
//
#include <hip/hip_runtime.h>
#include <math.h>

// Chamfer loss via MFMA (structure verified r12-r14, absmax 0).
// ROUND 15 = INSTRUMENTATION ROUND: the sweep's inner loop is repeated
// REPS=5 times (idempotent min over the same tile set; opaque asm on the
// base pointer per rep defeats load-CSE). Purpose: the harness's 268MB
// d_ws poison fills (~40us) crowd the sweep out of rocprof's top-5; at
// ~5x duration the sweep becomes top-1 and exposes its true VGPR_Count /
// VALUBusy / MfmaUtil. Total dur also discriminates: total ~= 39 + 4*S.
// Everything else is byte-identical to round 14.

typedef __attribute__((ext_vector_type(8)))  short  short8;
typedef __attribute__((ext_vector_type(16))) float  f32x16;

#define YS      4     // j-range splits per (dir,b)
#define RPB     256   // rows per block = 4 waves * 64 (2 strips/wave)
#define REPS    5     // instrumentation: inner-loop repeats (idempotent)

// 2 MFMAs (one A-strip x 2 j-tiles), C=0 inline, early-clobber outputs,
// 16 cycles of s_nop before any VALU read of the results.
#define MFMA2(da, db, A, B0, B1) \
    asm("v_mfma_f32_32x32x16_bf16 %0, %2, %3, 0\n\t" \
        "v_mfma_f32_32x32x16_bf16 %1, %2, %4, 0\n\t" \
        "s_nop 7\n\t" \
        "s_nop 7" \
        : "=&v"(da), "=&v"(db) \
        : "v"(A), "v"(B0), "v"(B1))

static inline int roundup_h(int v, int a) { return (v + a - 1) / a * a; }

static __device__ __forceinline__ unsigned short f2bf(float f) {
    union { float f; unsigned int u; } v; v.f = f;
    unsigned int r = v.u + 0x7FFFu + ((v.u >> 16) & 1u);  // RNE
    return (unsigned short)(r >> 16);
}
static __device__ __forceinline__ float bf2f(unsigned short s) {
    union { unsigned int u; float f; } v; v.u = ((unsigned int)s) << 16;
    return v.f;
}
static __device__ __forceinline__ unsigned int pk2(unsigned short lo,
                                                   unsigned short hi) {
    return (unsigned int)lo | ((unsigned int)hi << 16);
}

// all-reduce min over each 32-lane group: 4 DPP levels (VALU) + 1 swizzle
static __device__ __forceinline__ float allmin32(float v) {
    union { float f; int i; } u, t;
    u.f = v;
    t.i = __builtin_amdgcn_update_dpp(u.i, u.i, 0xB1, 0xF, 0xF, false);  // xor1
    u.f = fminf(u.f, t.f);
    t.i = __builtin_amdgcn_update_dpp(u.i, u.i, 0x4E, 0xF, 0xF, false);  // xor2
    u.f = fminf(u.f, t.f);
    t.i = __builtin_amdgcn_update_dpp(u.i, u.i, 0x124, 0xF, 0xF, false); // ror4
    u.f = fminf(u.f, t.f);
    t.i = __builtin_amdgcn_update_dpp(u.i, u.i, 0x128, 0xF, 0xF, false); // ror8
    u.f = fminf(u.f, t.f);
    t.i = __builtin_amdgcn_ds_swizzle(u.i, 0x401F);                      // xor16
    u.f = fminf(u.f, t.f);
    return u.f;
}

// A layout: per point i: 16 bf16 (two 16B halves, khalf h at +8 shorts).
// B layout: per (b): [tile][khalf][point] 16B units (tile=i>>5, p=i&31)
//  -> lane l's direct global read at tile*1024B + l*16B yields
//     point=l&31, khalf=l>>5, exactly the MFMA B-fragment.
__global__ __launch_bounds__(256) void pack_kernel(
    const float* __restrict__ pred, const float* __restrict__ targ,
    int B, int N, int M, int NpadP, int NpadT,
    unsigned short* __restrict__ aP, unsigned short* __restrict__ bP,
    unsigned short* __restrict__ aT, unsigned short* __restrict__ bT)
{
    const int padmax = (NpadP > NpadT) ? NpadP : NpadT;
    const int gid = blockIdx.x * 256 + threadIdx.x;
    if (gid >= B * padmax) return;
    const int b = gid / padmax, i = gid - b * padmax;

    for (int cloud = 0; cloud < 2; ++cloud) {
        const int cnt  = cloud ? M : N;
        const int npad = cloud ? NpadT : NpadP;
        if (i >= npad) continue;
        // padding duplicates the last point: harmless for min reductions
        const float* src = (cloud ? targ : pred) +
                           ((size_t)b * cnt + min(i, cnt - 1)) * 3;
        unsigned short* A  = (cloud ? aT : aP) + ((size_t)b * npad + i) * 16;
        unsigned short* Bk = (cloud ? bT : bP) + (size_t)b * npad * 16;

        const float xs[3] = {src[0], src[1], src[2]};
        const float n2 = xs[0]*xs[0] + xs[1]*xs[1] + xs[2]*xs[2];
        unsigned short th[3], tl[3], yh[3], yl[3];
        #pragma unroll
        for (int c = 0; c < 3; ++c) {
            const float t = -2.0f * xs[c];
            th[c] = f2bf(t);     tl[c] = f2bf(t - bf2f(th[c]));
            yh[c] = f2bf(xs[c]); yl[c] = f2bf(xs[c] - bf2f(yh[c]));
        }
        const unsigned short n2h = f2bf(n2);
        const unsigned short n2l = f2bf(n2 - bf2f(n2h));
        const unsigned short ONE = 0x3F80;

        uint4 alo, ahi, blo, bhi;
        alo.x = pk2(th[0], th[1]); alo.y = pk2(th[2], tl[0]);
        alo.z = pk2(tl[1], tl[2]); alo.w = pk2(th[0], th[1]);
        ahi.x = pk2(th[2], tl[0]); ahi.y = pk2(tl[1], tl[2]);
        ahi.z = pk2(ONE,  ONE);    ahi.w = pk2(n2h,  n2l);
        blo.x = pk2(yh[0], yh[1]); blo.y = pk2(yh[2], yh[0]);
        blo.z = pk2(yh[1], yh[2]); blo.w = pk2(yl[0], yl[1]);
        bhi.x = pk2(yl[2], yl[0]); bhi.y = pk2(yl[1], yl[2]);
        bhi.z = pk2(n2h,  n2l);    bhi.w = pk2(ONE,  ONE);

        *(uint4*)(A)     = alo;  *(uint4*)(A + 8) = ahi;
        const size_t tb = (size_t)(i >> 5) * 64 + (i & 31);   // 16B units
        *(uint4*)(Bk + tb * 8)        = blo;                   // khalf 0
        *(uint4*)(Bk + (tb + 32) * 8) = bhi;                   // khalf 1
    }
}

// Block = (dir, b, js, row-block of 256). 4 waves; wave w owns 64 rows
// (2 MFMA strips). B-fragments read DIRECTLY from global (L1/L2-resident,
// coalesced 1KB wave-loads), 1-deep prefetch. No LDS, no barriers.
// INSTRUMENTED: whole j-loop repeated REPS times (idempotent).
__global__ __launch_bounds__(256, 4) void mfma_sweep(
    const unsigned short* __restrict__ aP, const unsigned short* __restrict__ bP,
    const unsigned short* __restrict__ aT, const unsigned short* __restrict__ bT,
    int B, int N, int M, int NpadP, int NpadT, int NpadMax,
    float* __restrict__ rowpart)
{
    const int tid  = threadIdx.x;
    const int w    = tid >> 6;
    const int lane = tid & 63;
    const int lc   = lane & 31, h = lane >> 5;

    const int SP = NpadMax / RPB;
    int t = blockIdx.x;
    const int sp  = t % SP;  t /= SP;
    const int js  = t % YS;  t /= YS;
    const int b   = t % B;   t /= B;
    const int dir = t;

    const unsigned short* Xp = (dir == 0) ? aP : aT;
    const unsigned short* Yp = (dir == 0) ? bT : bP;
    const int NpadX = (dir == 0) ? NpadP : NpadT;
    const int NpadY = (dir == 0) ? NpadT : NpadP;
    const int Nx    = (dir == 0) ? N : M;
    if (sp * RPB >= NpadX) return;          // block-uniform

    // NpadY is a multiple of 256 -> TM mult of 8 -> nt0 even, chunks equal
    const int TM  = NpadY / 32;
    const int nt0 = TM / YS;
    const int t0  = js * nt0;

    // A-frags (loop-invariant): row = lane&31, k = (lane>>5)*8 + e
    const int row0 = sp * RPB + w * 64;
    const size_t abase = ((size_t)b * NpadX + row0 + lc) * 16 + (size_t)h * 8;
    const short8 a0 = *reinterpret_cast<const short8*>(Xp + abase);
    const short8 a1 = *reinterpret_cast<const short8*>(Xp + abase + 32 * 16);

    f32x16 rm0, rm1;
    #pragma unroll
    for (int r = 0; r < 16; ++r) {
        rm0[r] = __builtin_inff(); rm1[r] = __builtin_inff();
    }

    const unsigned short* ypb =
        Yp + (size_t)b * NpadY * 16 + (size_t)t0 * 512 + (size_t)lane * 8;

    for (int rep = 0; rep < REPS; ++rep) {
        const unsigned short* yp = ypb;
        asm("" : "+v"(yp));              // opaque: defeat cross-rep load CSE
        short8 c0 = *reinterpret_cast<const short8*>(yp);
        short8 c1 = *reinterpret_cast<const short8*>(yp + 512);

        for (int j = 0; j < nt0; j += 2) {
            // prefetch next pair (last iter reads <=2 tiles past the chunk:
            // covered by the 8KB slack after each pack buffer)
            const short8 n0 = *reinterpret_cast<const short8*>(yp + 1024);
            const short8 n1 = *reinterpret_cast<const short8*>(yp + 1536);
            yp += 1024;
            __builtin_amdgcn_sched_barrier(0);   // keep prefetch issued early
            {   // strip 0 (transient 32-reg D, then fold)
                f32x16 da, db;
                MFMA2(da, db, a0, c0, c1);
                #pragma unroll
                for (int r = 0; r < 16; ++r)      // fuses to v_min3_f32
                    rm0[r] = fminf(fminf(da[r], db[r]), rm0[r]);
            }
            {   // strip 1
                f32x16 da, db;
                MFMA2(da, db, a1, c0, c1);
                #pragma unroll
                for (int r = 0; r < 16; ++r)
                    rm1[r] = fminf(fminf(da[r], db[r]), rm1[r]);
            }
            c0 = n0; c1 = n1;
        }
    }

    // per-row min over 32 cols (DPP+swizzle all-reduce), then store.
    // D layout: col=lane&31, row=(r&3)+8*(r>>2)+4*(lane>>5)
    const size_t outb = (((size_t)dir * B + b) * YS + js) * (size_t)NpadMax;
    #pragma unroll
    for (int r = 0; r < 16; ++r) {
        const float v0 = allmin32(rm0[r]);
        const float v1 = allmin32(rm1[r]);
        if (lc == 0) {
            const int rr = (r & 3) + 8 * (r >> 2) + 4 * h;
            const int ra = row0 + rr, rb = row0 + 32 + rr;
            if (ra < Nx) rowpart[outb + ra] = v0;
            if (rb < Nx) rowpart[outb + rb] = v1;
        }
    }
}

__global__ __launch_bounds__(256) void combine_kernel(
    const float* __restrict__ rowpart, int B, int N, int M,
    int NpadP, int NpadT, int NpadMax,
    float invBN, float invBM, float* __restrict__ partial)
{
    const int tid = threadIdx.x;
    const int tot = 2 * B * NpadMax;
    float acc = 0.f;
    for (int idx = blockIdx.x * 256 + tid; idx < tot; idx += gridDim.x * 256) {
        const int row = idx % NpadMax;
        const int rem = idx / NpadMax;
        const int b   = rem % B;
        const int dir = rem / B;
        const int Nx  = (dir == 0) ? N : M;
        if (row >= Nx) continue;
        float m = __builtin_inff();
        #pragma unroll
        for (int js = 0; js < YS; ++js)
            m = fminf(m, rowpart[(((size_t)dir * B + b) * YS + js)
                                 * (size_t)NpadMax + row]);
        acc += fmaxf(m, 0.f) * ((dir == 0) ? invBN : invBM);
    }
    __shared__ float sb[256];
    sb[tid] = acc; __syncthreads();
    for (int off2 = 128; off2 > 0; off2 >>= 1) {
        if (tid < off2) sb[tid] += sb[tid + off2];
        __syncthreads();
    }
    if (tid == 0) partial[blockIdx.x] = sb[0];
}

__global__ void finalize_kernel(const float* __restrict__ partial, int np,
                                const float* __restrict__ fbpp, int Bf,
                                const void* __restrict__ lamp,
                                float* __restrict__ out)
{
    __shared__ float sb[256];
    const int tid = threadIdx.x;
    float acc = 0.f;
    for (int i = tid; i < np; i += 256) acc += partial[i];
    sb[tid] = acc;
    __syncthreads();
    for (int off = 128; off > 0; off >>= 1) {
        if (tid < off) sb[tid] += sb[tid + off];
        __syncthreads();
    }
    if (tid == 0) {
        const int li = *(const int*)lamp;
        const float lam = (li >= -1000000 && li <= 1000000)
                            ? (float)li : *(const float*)lamp;
        float fm = 0.f;
        for (int i = 0; i < Bf; ++i) fm += fbpp[i];
        fm /= (float)Bf;
        out[0] = sb[0] + lam * fm;
    }
}

extern "C" void kernel_launch(void* const* d_in, const int* in_sizes, int n_in,
                              void* d_out, int out_size, void* d_ws, size_t ws_size,
                              hipStream_t stream) {
    const float* pred = (const float*)d_in[0];
    const float* targ = (const float*)d_in[1];
    const float* fbpp = (const float*)d_in[2];
    const void*  lamp = d_in[3];

    const int B = in_sizes[2];
    const int N = in_sizes[0] / (3 * B);
    const int M = in_sizes[1] / (3 * B);
    const int NpadP = roundup_h(N, RPB);
    const int NpadT = roundup_h(M, RPB);
    const int NpadMax = (NpadP > NpadT) ? NpadP : NpadT;

    // ---- workspace layout (+8KB slack after each pack for prefetch OOB) ----
    size_t o = 0;
    auto take = [&](size_t bytes) {
        size_t r = o; o += (bytes + 255) & ~(size_t)255; return r;
    };
    unsigned short* aP = (unsigned short*)((char*)d_ws +
                         take((size_t)B * NpadP * 32 + 8192));
    unsigned short* bP = (unsigned short*)((char*)d_ws +
                         take((size_t)B * NpadP * 32 + 8192));
    unsigned short* aT = (unsigned short*)((char*)d_ws +
                         take((size_t)B * NpadT * 32 + 8192));
    unsigned short* bT = (unsigned short*)((char*)d_ws +
                         take((size_t)B * NpadT * 32 + 8192));
    float* rowpart = (float*)((char*)d_ws +
                     take((size_t)2 * B * YS * NpadMax * sizeof(float)));
    float* partial = (float*)((char*)d_ws + take(256 * sizeof(float)));
    (void)ws_size;

    // ---- 1) pack both clouds into A/B MFMA K-patterns ----
    pack_kernel<<<(B * NpadMax + 255) / 256, 256, 0, stream>>>(
        pred, targ, B, N, M, NpadP, NpadT, aP, bP, aT, bT);

    // ---- 2) MFMA pair sweep (both directions), REPS-instrumented ----
    const int SP = NpadMax / RPB;
    const int blocks = 2 * B * YS * SP;
    mfma_sweep<<<blocks, 256, 0, stream>>>(
        aP, bP, aT, bT, B, N, M, NpadP, NpadT, NpadMax, rowpart);

    // ---- 3) combine splits + clamp + weighted sum ----
    combine_kernel<<<256, 256, 0, stream>>>(
        rowpart, B, N, M, NpadP, NpadT, NpadMax,
        1.f / ((float)B * (float)N), 1.f / ((float)B * (float)M), partial);

    // ---- 4) finalize ----
    finalize_kernel<<<1, 256, 0, stream>>>(partial, 256, fbpp, B, lamp,
                                           (float*)d_out);
}

// Round 16
// 40.856 us; speedup vs baseline: 2.6311x; 2.6311x over previous
//
#include <hip/hip_runtime.h>
#include <math.h>

// Chamfer loss via MFMA (structure verified r12-r15, absmax 0).
// Round-16 vs r14 (r15 instrumentation findings): sweep = ~16us cold-latency
// + ~17us warm loop, Occupancy 35%, VALUBusy 53%, MfmaUtil 37% -> stall-
// bound at 4 waves/SIMD, not pipe-bound. Fix: YS 4->8 (2048 blocks = 8
// blocks/CU = 8 waves/SIMD) + 2-pair-deep prefetch pipeline (4 loads in
// flight, no OOB by construction). Others (pack/combine/finalize+gaps)
// measured ~5.5us total - left alone.

typedef __attribute__((ext_vector_type(8)))  short  short8;
typedef __attribute__((ext_vector_type(16))) float  f32x16;

#define YS      8     // j-range splits per (dir,b)
#define RPB     256   // rows per block = 4 waves * 64 (2 strips/wave)

// 2 MFMAs (one A-strip x 2 j-tiles), C=0 inline, early-clobber outputs,
// 16 cycles of s_nop before any VALU read of the results.
#define MFMA2(da, db, A, B0, B1) \
    asm("v_mfma_f32_32x32x16_bf16 %0, %2, %3, 0\n\t" \
        "v_mfma_f32_32x32x16_bf16 %1, %2, %4, 0\n\t" \
        "s_nop 7\n\t" \
        "s_nop 7" \
        : "=&v"(da), "=&v"(db) \
        : "v"(A), "v"(B0), "v"(B1))

// both strips on a tile pair (p0,p1), folding into rm0/rm1
#define WORKPAIR(p0, p1) do { \
    { f32x16 da, db; MFMA2(da, db, a0, p0, p1); \
      _Pragma("unroll") \
      for (int r = 0; r < 16; ++r) \
          rm0[r] = fminf(fminf(da[r], db[r]), rm0[r]); } \
    { f32x16 da, db; MFMA2(da, db, a1, p0, p1); \
      _Pragma("unroll") \
      for (int r = 0; r < 16; ++r) \
          rm1[r] = fminf(fminf(da[r], db[r]), rm1[r]); } \
} while (0)

static inline int roundup_h(int v, int a) { return (v + a - 1) / a * a; }

static __device__ __forceinline__ unsigned short f2bf(float f) {
    union { float f; unsigned int u; } v; v.f = f;
    unsigned int r = v.u + 0x7FFFu + ((v.u >> 16) & 1u);  // RNE
    return (unsigned short)(r >> 16);
}
static __device__ __forceinline__ float bf2f(unsigned short s) {
    union { unsigned int u; float f; } v; v.u = ((unsigned int)s) << 16;
    return v.f;
}
static __device__ __forceinline__ unsigned int pk2(unsigned short lo,
                                                   unsigned short hi) {
    return (unsigned int)lo | ((unsigned int)hi << 16);
}

// all-reduce min over each 32-lane group: 4 DPP levels (VALU) + 1 swizzle
static __device__ __forceinline__ float allmin32(float v) {
    union { float f; int i; } u, t;
    u.f = v;
    t.i = __builtin_amdgcn_update_dpp(u.i, u.i, 0xB1, 0xF, 0xF, false);  // xor1
    u.f = fminf(u.f, t.f);
    t.i = __builtin_amdgcn_update_dpp(u.i, u.i, 0x4E, 0xF, 0xF, false);  // xor2
    u.f = fminf(u.f, t.f);
    t.i = __builtin_amdgcn_update_dpp(u.i, u.i, 0x124, 0xF, 0xF, false); // ror4
    u.f = fminf(u.f, t.f);
    t.i = __builtin_amdgcn_update_dpp(u.i, u.i, 0x128, 0xF, 0xF, false); // ror8
    u.f = fminf(u.f, t.f);
    t.i = __builtin_amdgcn_ds_swizzle(u.i, 0x401F);                      // xor16
    u.f = fminf(u.f, t.f);
    return u.f;
}

// A layout: per point i: 16 bf16 (two 16B halves, khalf h at +8 shorts).
// B layout: per (b): [tile][khalf][point] 16B units (tile=i>>5, p=i&31)
//  -> lane l's direct global read at tile*1024B + l*16B yields
//     point=l&31, khalf=l>>5, exactly the MFMA B-fragment.
__global__ __launch_bounds__(256) void pack_kernel(
    const float* __restrict__ pred, const float* __restrict__ targ,
    int B, int N, int M, int NpadP, int NpadT,
    unsigned short* __restrict__ aP, unsigned short* __restrict__ bP,
    unsigned short* __restrict__ aT, unsigned short* __restrict__ bT)
{
    const int padmax = (NpadP > NpadT) ? NpadP : NpadT;
    const int gid = blockIdx.x * 256 + threadIdx.x;
    if (gid >= B * padmax) return;
    const int b = gid / padmax, i = gid - b * padmax;

    for (int cloud = 0; cloud < 2; ++cloud) {
        const int cnt  = cloud ? M : N;
        const int npad = cloud ? NpadT : NpadP;
        if (i >= npad) continue;
        // padding duplicates the last point: harmless for min reductions
        const float* src = (cloud ? targ : pred) +
                           ((size_t)b * cnt + min(i, cnt - 1)) * 3;
        unsigned short* A  = (cloud ? aT : aP) + ((size_t)b * npad + i) * 16;
        unsigned short* Bk = (cloud ? bT : bP) + (size_t)b * npad * 16;

        const float xs[3] = {src[0], src[1], src[2]};
        const float n2 = xs[0]*xs[0] + xs[1]*xs[1] + xs[2]*xs[2];
        unsigned short th[3], tl[3], yh[3], yl[3];
        #pragma unroll
        for (int c = 0; c < 3; ++c) {
            const float t = -2.0f * xs[c];
            th[c] = f2bf(t);     tl[c] = f2bf(t - bf2f(th[c]));
            yh[c] = f2bf(xs[c]); yl[c] = f2bf(xs[c] - bf2f(yh[c]));
        }
        const unsigned short n2h = f2bf(n2);
        const unsigned short n2l = f2bf(n2 - bf2f(n2h));
        const unsigned short ONE = 0x3F80;

        uint4 alo, ahi, blo, bhi;
        alo.x = pk2(th[0], th[1]); alo.y = pk2(th[2], tl[0]);
        alo.z = pk2(tl[1], tl[2]); alo.w = pk2(th[0], th[1]);
        ahi.x = pk2(th[2], tl[0]); ahi.y = pk2(tl[1], tl[2]);
        ahi.z = pk2(ONE,  ONE);    ahi.w = pk2(n2h,  n2l);
        blo.x = pk2(yh[0], yh[1]); blo.y = pk2(yh[2], yh[0]);
        blo.z = pk2(yh[1], yh[2]); blo.w = pk2(yl[0], yl[1]);
        bhi.x = pk2(yl[2], yl[0]); bhi.y = pk2(yl[1], yl[2]);
        bhi.z = pk2(n2h,  n2l);    bhi.w = pk2(ONE,  ONE);

        *(uint4*)(A)     = alo;  *(uint4*)(A + 8) = ahi;
        const size_t tb = (size_t)(i >> 5) * 64 + (i & 31);   // 16B units
        *(uint4*)(Bk + tb * 8)        = blo;                   // khalf 0
        *(uint4*)(Bk + (tb + 32) * 8) = bhi;                   // khalf 1
    }
}

// Block = (dir, b, js, row-block of 256). 4 waves; wave w owns 64 rows
// (2 MFMA strips). B-fragments read DIRECTLY from global (coalesced 1KB
// wave-loads), 2-pair-deep pipeline (4 loads in flight). No LDS/barriers.
__global__ __launch_bounds__(256, 4) void mfma_sweep(
    const unsigned short* __restrict__ aP, const unsigned short* __restrict__ bP,
    const unsigned short* __restrict__ aT, const unsigned short* __restrict__ bT,
    int B, int N, int M, int NpadP, int NpadT, int NpadMax,
    float* __restrict__ rowpart)
{
    const int tid  = threadIdx.x;
    const int w    = tid >> 6;
    const int lane = tid & 63;
    const int lc   = lane & 31, h = lane >> 5;

    const int SP = NpadMax / RPB;
    int t = blockIdx.x;
    const int sp  = t % SP;  t /= SP;
    const int js  = t % YS;  t /= YS;
    const int b   = t % B;   t /= B;
    const int dir = t;

    const unsigned short* Xp = (dir == 0) ? aP : aT;
    const unsigned short* Yp = (dir == 0) ? bT : bP;
    const int NpadX = (dir == 0) ? NpadP : NpadT;
    const int NpadY = (dir == 0) ? NpadT : NpadP;
    const int Nx    = (dir == 0) ? N : M;
    if (sp * RPB >= NpadX) return;          // block-uniform

    // NpadY is a multiple of 256 -> TM mult of 8 -> nt0 = TM/YS exact
    const int TM  = NpadY / 32;
    const int nt0 = TM / YS;
    const int t0  = js * nt0;

    // A-frags (loop-invariant): row = lane&31, k = (lane>>5)*8 + e
    const int row0 = sp * RPB + w * 64;
    const size_t abase = ((size_t)b * NpadX + row0 + lc) * 16 + (size_t)h * 8;
    const short8 a0 = *reinterpret_cast<const short8*>(Xp + abase);
    const short8 a1 = *reinterpret_cast<const short8*>(Xp + abase + 32 * 16);

    f32x16 rm0, rm1;
    #pragma unroll
    for (int r = 0; r < 16; ++r) {
        rm0[r] = __builtin_inff(); rm1[r] = __builtin_inff();
    }

    // B-frag stream: tile j at yp + j*512 shorts (tile stride = 1KB)
    const unsigned short* yp =
        Yp + (size_t)b * NpadY * 16 + (size_t)t0 * 512 + (size_t)lane * 8;

    int j = 0;
    if (nt0 >= 4) {
        short8 c0 = *reinterpret_cast<const short8*>(yp);
        short8 c1 = *reinterpret_cast<const short8*>(yp + 512);
        short8 d0 = *reinterpret_cast<const short8*>(yp + 1024);
        short8 d1 = *reinterpret_cast<const short8*>(yp + 1536);
        for (; j + 8 <= nt0; j += 4) {
            const short8 e0 = *reinterpret_cast<const short8*>(yp + 2048);
            const short8 e1 = *reinterpret_cast<const short8*>(yp + 2560);
            const short8 f0 = *reinterpret_cast<const short8*>(yp + 3072);
            const short8 f1 = *reinterpret_cast<const short8*>(yp + 3584);
            yp += 2048;
            __builtin_amdgcn_sched_barrier(0);  // keep prefetch issued early
            WORKPAIR(c0, c1);
            WORKPAIR(d0, d1);
            c0 = e0; c1 = e1; d0 = f0; d1 = f1;
        }
        // consume the final preloaded 4 tiles
        WORKPAIR(c0, c1);
        WORKPAIR(d0, d1);
        j += 4; yp += 2048;
    }
    for (; j + 2 <= nt0; j += 2) {   // small-nt0 / remainder pairs
        const short8 g0 = *reinterpret_cast<const short8*>(yp);
        const short8 g1 = *reinterpret_cast<const short8*>(yp + 512);
        WORKPAIR(g0, g1);
        yp += 1024;
    }
    if (j < nt0) {                    // odd single tile: pair with itself
        const short8 g0 = *reinterpret_cast<const short8*>(yp);
        WORKPAIR(g0, g0);
    }

    // per-row min over 32 cols (DPP+swizzle all-reduce), then store.
    // D layout: col=lane&31, row=(r&3)+8*(r>>2)+4*(lane>>5)
    const size_t outb = (((size_t)dir * B + b) * YS + js) * (size_t)NpadMax;
    #pragma unroll
    for (int r = 0; r < 16; ++r) {
        const float v0 = allmin32(rm0[r]);
        const float v1 = allmin32(rm1[r]);
        if (lc == 0) {
            const int rr = (r & 3) + 8 * (r >> 2) + 4 * h;
            const int ra = row0 + rr, rb = row0 + 32 + rr;
            if (ra < Nx) rowpart[outb + ra] = v0;
            if (rb < Nx) rowpart[outb + rb] = v1;
        }
    }
}

__global__ __launch_bounds__(256) void combine_kernel(
    const float* __restrict__ rowpart, int B, int N, int M,
    int NpadP, int NpadT, int NpadMax,
    float invBN, float invBM, float* __restrict__ partial)
{
    const int tid = threadIdx.x;
    const int tot = 2 * B * NpadMax;
    float acc = 0.f;
    for (int idx = blockIdx.x * 256 + tid; idx < tot; idx += gridDim.x * 256) {
        const int row = idx % NpadMax;
        const int rem = idx / NpadMax;
        const int b   = rem % B;
        const int dir = rem / B;
        const int Nx  = (dir == 0) ? N : M;
        if (row >= Nx) continue;
        float m = __builtin_inff();
        #pragma unroll
        for (int js = 0; js < YS; ++js)
            m = fminf(m, rowpart[(((size_t)dir * B + b) * YS + js)
                                 * (size_t)NpadMax + row]);
        acc += fmaxf(m, 0.f) * ((dir == 0) ? invBN : invBM);
    }
    __shared__ float sb[256];
    sb[tid] = acc; __syncthreads();
    for (int off2 = 128; off2 > 0; off2 >>= 1) {
        if (tid < off2) sb[tid] += sb[tid + off2];
        __syncthreads();
    }
    if (tid == 0) partial[blockIdx.x] = sb[0];
}

__global__ void finalize_kernel(const float* __restrict__ partial, int np,
                                const float* __restrict__ fbpp, int Bf,
                                const void* __restrict__ lamp,
                                float* __restrict__ out)
{
    __shared__ float sb[256];
    const int tid = threadIdx.x;
    float acc = 0.f;
    for (int i = tid; i < np; i += 256) acc += partial[i];
    sb[tid] = acc;
    __syncthreads();
    for (int off = 128; off > 0; off >>= 1) {
        if (tid < off) sb[tid] += sb[tid + off];
        __syncthreads();
    }
    if (tid == 0) {
        const int li = *(const int*)lamp;
        const float lam = (li >= -1000000 && li <= 1000000)
                            ? (float)li : *(const float*)lamp;
        float fm = 0.f;
        for (int i = 0; i < Bf; ++i) fm += fbpp[i];
        fm /= (float)Bf;
        out[0] = sb[0] + lam * fm;
    }
}

extern "C" void kernel_launch(void* const* d_in, const int* in_sizes, int n_in,
                              void* d_out, int out_size, void* d_ws, size_t ws_size,
                              hipStream_t stream) {
    const float* pred = (const float*)d_in[0];
    const float* targ = (const float*)d_in[1];
    const float* fbpp = (const float*)d_in[2];
    const void*  lamp = d_in[3];

    const int B = in_sizes[2];
    const int N = in_sizes[0] / (3 * B);
    const int M = in_sizes[1] / (3 * B);
    const int NpadP = roundup_h(N, RPB);
    const int NpadT = roundup_h(M, RPB);
    const int NpadMax = (NpadP > NpadT) ? NpadP : NpadT;

    // ---- workspace layout (+8KB slack after each pack, defensive) ----
    size_t o = 0;
    auto take = [&](size_t bytes) {
        size_t r = o; o += (bytes + 255) & ~(size_t)255; return r;
    };
    unsigned short* aP = (unsigned short*)((char*)d_ws +
                         take((size_t)B * NpadP * 32 + 8192));
    unsigned short* bP = (unsigned short*)((char*)d_ws +
                         take((size_t)B * NpadP * 32 + 8192));
    unsigned short* aT = (unsigned short*)((char*)d_ws +
                         take((size_t)B * NpadT * 32 + 8192));
    unsigned short* bT = (unsigned short*)((char*)d_ws +
                         take((size_t)B * NpadT * 32 + 8192));
    float* rowpart = (float*)((char*)d_ws +
                     take((size_t)2 * B * YS * NpadMax * sizeof(float)));
    float* partial = (float*)((char*)d_ws + take(256 * sizeof(float)));
    (void)ws_size;

    // ---- 1) pack both clouds into A/B MFMA K-patterns ----
    pack_kernel<<<(B * NpadMax + 255) / 256, 256, 0, stream>>>(
        pred, targ, B, N, M, NpadP, NpadT, aP, bP, aT, bT);

    // ---- 2) MFMA pair sweep (both directions) ----
    const int SP = NpadMax / RPB;
    const int blocks = 2 * B * YS * SP;
    mfma_sweep<<<blocks, 256, 0, stream>>>(
        aP, bP, aT, bT, B, N, M, NpadP, NpadT, NpadMax, rowpart);

    // ---- 3) combine splits + clamp + weighted sum ----
    combine_kernel<<<256, 256, 0, stream>>>(
        rowpart, B, N, M, NpadP, NpadT, NpadMax,
        1.f / ((float)B * (float)N), 1.f / ((float)B * (float)M), partial);

    // ---- 4) finalize ----
    finalize_kernel<<<1, 256, 0, stream>>>(partial, 256, fbpp, B, lamp,
                                           (float*)d_out);
}

// Round 17
// 38.400 us; speedup vs baseline: 2.7993x; 1.0640x over previous
//
#include <hip/hip_runtime.h>
#include <math.h>

// Chamfer loss via MFMA (structure verified r12-r16, absmax 0).
// Round-17 vs round 14 (ONE variable): the accumulator fold uses inline-asm
// v_min3_f32 instead of fminf(fminf(..)..). hipcc without fast-math CANNOT
// fuse fminf chains to v_min3 (NaN semantics) and adds canonicalization ->
// ~5 VALU per intended min3. That is the r15 warm-loop mystery: measured
// ~17us/rep vs ~3.8us issue model (4.5x = the fminf bloat), VALUBusy 53%
// with MfmaUtil 37%. r16's occupancy/pipeline-depth probes were null,
// consistent: the loop was VALU-issue-bound via codegen bloat.

typedef __attribute__((ext_vector_type(8)))  short  short8;
typedef __attribute__((ext_vector_type(16))) float  f32x16;

#define YS      4     // j-range splits per (dir,b)
#define RPB     256   // rows per block = 4 waves * 64 (2 strips/wave)

// 2 MFMAs (one A-strip x 2 j-tiles), C=0 inline, early-clobber outputs,
// 16 cycles of s_nop before any VALU read of the results.
#define MFMA2(da, db, A, B0, B1) \
    asm("v_mfma_f32_32x32x16_bf16 %0, %2, %3, 0\n\t" \
        "v_mfma_f32_32x32x16_bf16 %1, %2, %4, 0\n\t" \
        "s_nop 7\n\t" \
        "s_nop 7" \
        : "=&v"(da), "=&v"(db) \
        : "v"(A), "v"(B0), "v"(B1))

// single-instruction 3-input min (no canonicalize, no NaN path; inputs finite)
static __device__ __forceinline__ float min3f(float a, float b, float c) {
    float d;
    asm("v_min3_f32 %0, %1, %2, %3" : "=v"(d) : "v"(a), "v"(b), "v"(c));
    return d;
}

static inline int roundup_h(int v, int a) { return (v + a - 1) / a * a; }

static __device__ __forceinline__ unsigned short f2bf(float f) {
    union { float f; unsigned int u; } v; v.f = f;
    unsigned int r = v.u + 0x7FFFu + ((v.u >> 16) & 1u);  // RNE
    return (unsigned short)(r >> 16);
}
static __device__ __forceinline__ float bf2f(unsigned short s) {
    union { unsigned int u; float f; } v; v.u = ((unsigned int)s) << 16;
    return v.f;
}
static __device__ __forceinline__ unsigned int pk2(unsigned short lo,
                                                   unsigned short hi) {
    return (unsigned int)lo | ((unsigned int)hi << 16);
}

// all-reduce min over each 32-lane group: 4 DPP levels (VALU) + 1 swizzle
static __device__ __forceinline__ float allmin32(float v) {
    union { float f; int i; } u, t;
    u.f = v;
    t.i = __builtin_amdgcn_update_dpp(u.i, u.i, 0xB1, 0xF, 0xF, false);  // xor1
    u.f = fminf(u.f, t.f);
    t.i = __builtin_amdgcn_update_dpp(u.i, u.i, 0x4E, 0xF, 0xF, false);  // xor2
    u.f = fminf(u.f, t.f);
    t.i = __builtin_amdgcn_update_dpp(u.i, u.i, 0x124, 0xF, 0xF, false); // ror4
    u.f = fminf(u.f, t.f);
    t.i = __builtin_amdgcn_update_dpp(u.i, u.i, 0x128, 0xF, 0xF, false); // ror8
    u.f = fminf(u.f, t.f);
    t.i = __builtin_amdgcn_ds_swizzle(u.i, 0x401F);                      // xor16
    u.f = fminf(u.f, t.f);
    return u.f;
}

// A layout: per point i: 16 bf16 (two 16B halves, khalf h at +8 shorts).
// B layout: per (b): [tile][khalf][point] 16B units (tile=i>>5, p=i&31)
//  -> lane l's direct global read at tile*1024B + l*16B yields
//     point=l&31, khalf=l>>5, exactly the MFMA B-fragment.
__global__ __launch_bounds__(256) void pack_kernel(
    const float* __restrict__ pred, const float* __restrict__ targ,
    int B, int N, int M, int NpadP, int NpadT,
    unsigned short* __restrict__ aP, unsigned short* __restrict__ bP,
    unsigned short* __restrict__ aT, unsigned short* __restrict__ bT)
{
    const int padmax = (NpadP > NpadT) ? NpadP : NpadT;
    const int gid = blockIdx.x * 256 + threadIdx.x;
    if (gid >= B * padmax) return;
    const int b = gid / padmax, i = gid - b * padmax;

    for (int cloud = 0; cloud < 2; ++cloud) {
        const int cnt  = cloud ? M : N;
        const int npad = cloud ? NpadT : NpadP;
        if (i >= npad) continue;
        // padding duplicates the last point: harmless for min reductions
        const float* src = (cloud ? targ : pred) +
                           ((size_t)b * cnt + min(i, cnt - 1)) * 3;
        unsigned short* A  = (cloud ? aT : aP) + ((size_t)b * npad + i) * 16;
        unsigned short* Bk = (cloud ? bT : bP) + (size_t)b * npad * 16;

        const float xs[3] = {src[0], src[1], src[2]};
        const float n2 = xs[0]*xs[0] + xs[1]*xs[1] + xs[2]*xs[2];
        unsigned short th[3], tl[3], yh[3], yl[3];
        #pragma unroll
        for (int c = 0; c < 3; ++c) {
            const float t = -2.0f * xs[c];
            th[c] = f2bf(t);     tl[c] = f2bf(t - bf2f(th[c]));
            yh[c] = f2bf(xs[c]); yl[c] = f2bf(xs[c] - bf2f(yh[c]));
        }
        const unsigned short n2h = f2bf(n2);
        const unsigned short n2l = f2bf(n2 - bf2f(n2h));
        const unsigned short ONE = 0x3F80;

        uint4 alo, ahi, blo, bhi;
        alo.x = pk2(th[0], th[1]); alo.y = pk2(th[2], tl[0]);
        alo.z = pk2(tl[1], tl[2]); alo.w = pk2(th[0], th[1]);
        ahi.x = pk2(th[2], tl[0]); ahi.y = pk2(tl[1], tl[2]);
        ahi.z = pk2(ONE,  ONE);    ahi.w = pk2(n2h,  n2l);
        blo.x = pk2(yh[0], yh[1]); blo.y = pk2(yh[2], yh[0]);
        blo.z = pk2(yh[1], yh[2]); blo.w = pk2(yl[0], yl[1]);
        bhi.x = pk2(yl[2], yl[0]); bhi.y = pk2(yl[1], yl[2]);
        bhi.z = pk2(n2h,  n2l);    bhi.w = pk2(ONE,  ONE);

        *(uint4*)(A)     = alo;  *(uint4*)(A + 8) = ahi;
        const size_t tb = (size_t)(i >> 5) * 64 + (i & 31);   // 16B units
        *(uint4*)(Bk + tb * 8)        = blo;                   // khalf 0
        *(uint4*)(Bk + (tb + 32) * 8) = bhi;                   // khalf 1
    }
}

// Block = (dir, b, js, row-block of 256). 4 waves; wave w owns 64 rows
// (2 MFMA strips). B-fragments read DIRECTLY from global (L1/L2-resident,
// coalesced 1KB wave-loads), 1-deep prefetch. No LDS, no barriers.
// Inner (per 2 y-tiles): 2 loads + 2x(MFMA2 + 16 asm v_min3).
__global__ __launch_bounds__(256, 4) void mfma_sweep(
    const unsigned short* __restrict__ aP, const unsigned short* __restrict__ bP,
    const unsigned short* __restrict__ aT, const unsigned short* __restrict__ bT,
    int B, int N, int M, int NpadP, int NpadT, int NpadMax,
    float* __restrict__ rowpart)
{
    const int tid  = threadIdx.x;
    const int w    = tid >> 6;
    const int lane = tid & 63;
    const int lc   = lane & 31, h = lane >> 5;

    const int SP = NpadMax / RPB;
    int t = blockIdx.x;
    const int sp  = t % SP;  t /= SP;
    const int js  = t % YS;  t /= YS;
    const int b   = t % B;   t /= B;
    const int dir = t;

    const unsigned short* Xp = (dir == 0) ? aP : aT;
    const unsigned short* Yp = (dir == 0) ? bT : bP;
    const int NpadX = (dir == 0) ? NpadP : NpadT;
    const int NpadY = (dir == 0) ? NpadT : NpadP;
    const int Nx    = (dir == 0) ? N : M;
    if (sp * RPB >= NpadX) return;          // block-uniform

    // NpadY is a multiple of 256 -> TM mult of 8 -> nt0 = TM/YS exact
    const int TM  = NpadY / 32;
    const int nt0 = TM / YS;
    const int t0  = js * nt0;

    // A-frags (loop-invariant): row = lane&31, k = (lane>>5)*8 + e
    const int row0 = sp * RPB + w * 64;
    const size_t abase = ((size_t)b * NpadX + row0 + lc) * 16 + (size_t)h * 8;
    const short8 a0 = *reinterpret_cast<const short8*>(Xp + abase);
    const short8 a1 = *reinterpret_cast<const short8*>(Xp + abase + 32 * 16);

    f32x16 rm0, rm1;
    #pragma unroll
    for (int r = 0; r < 16; ++r) {
        rm0[r] = __builtin_inff(); rm1[r] = __builtin_inff();
    }

    // B-frag stream: tile j at yp + j*512 shorts (tile stride = 1KB)
    const unsigned short* yp =
        Yp + (size_t)b * NpadY * 16 + (size_t)t0 * 512 + (size_t)lane * 8;
    short8 c0 = *reinterpret_cast<const short8*>(yp);
    short8 c1 = *reinterpret_cast<const short8*>(yp + 512);

    for (int j = 0; j < nt0; j += 2) {
        // prefetch next pair (last iter reads <=2 tiles past the chunk:
        // covered by the 8KB slack after each pack buffer)
        const short8 n0 = *reinterpret_cast<const short8*>(yp + 1024);
        const short8 n1 = *reinterpret_cast<const short8*>(yp + 1536);
        yp += 1024;
        __builtin_amdgcn_sched_barrier(0);   // keep prefetch issued early
        {   // strip 0 (transient 32-reg D, then fold)
            f32x16 da, db;
            MFMA2(da, db, a0, c0, c1);
            #pragma unroll
            for (int r = 0; r < 16; ++r)
                rm0[r] = min3f(da[r], db[r], rm0[r]);   // 1 instr each
        }
        {   // strip 1
            f32x16 da, db;
            MFMA2(da, db, a1, c0, c1);
            #pragma unroll
            for (int r = 0; r < 16; ++r)
                rm1[r] = min3f(da[r], db[r], rm1[r]);
        }
        c0 = n0; c1 = n1;
    }

    // per-row min over 32 cols (DPP+swizzle all-reduce), then store.
    // D layout: col=lane&31, row=(r&3)+8*(r>>2)+4*(lane>>5)
    const size_t outb = (((size_t)dir * B + b) * YS + js) * (size_t)NpadMax;
    #pragma unroll
    for (int r = 0; r < 16; ++r) {
        const float v0 = allmin32(rm0[r]);
        const float v1 = allmin32(rm1[r]);
        if (lc == 0) {
            const int rr = (r & 3) + 8 * (r >> 2) + 4 * h;
            const int ra = row0 + rr, rb = row0 + 32 + rr;
            if (ra < Nx) rowpart[outb + ra] = v0;
            if (rb < Nx) rowpart[outb + rb] = v1;
        }
    }
}

__global__ __launch_bounds__(256) void combine_kernel(
    const float* __restrict__ rowpart, int B, int N, int M,
    int NpadP, int NpadT, int NpadMax,
    float invBN, float invBM, float* __restrict__ partial)
{
    const int tid = threadIdx.x;
    const int tot = 2 * B * NpadMax;
    float acc = 0.f;
    for (int idx = blockIdx.x * 256 + tid; idx < tot; idx += gridDim.x * 256) {
        const int row = idx % NpadMax;
        const int rem = idx / NpadMax;
        const int b   = rem % B;
        const int dir = rem / B;
        const int Nx  = (dir == 0) ? N : M;
        if (row >= Nx) continue;
        float m = __builtin_inff();
        #pragma unroll
        for (int js = 0; js < YS; ++js)
            m = fminf(m, rowpart[(((size_t)dir * B + b) * YS + js)
                                 * (size_t)NpadMax + row]);
        acc += fmaxf(m, 0.f) * ((dir == 0) ? invBN : invBM);
    }
    __shared__ float sb[256];
    sb[tid] = acc; __syncthreads();
    for (int off2 = 128; off2 > 0; off2 >>= 1) {
        if (tid < off2) sb[tid] += sb[tid + off2];
        __syncthreads();
    }
    if (tid == 0) partial[blockIdx.x] = sb[0];
}

__global__ void finalize_kernel(const float* __restrict__ partial, int np,
                                const float* __restrict__ fbpp, int Bf,
                                const void* __restrict__ lamp,
                                float* __restrict__ out)
{
    __shared__ float sb[256];
    const int tid = threadIdx.x;
    float acc = 0.f;
    for (int i = tid; i < np; i += 256) acc += partial[i];
    sb[tid] = acc;
    __syncthreads();
    for (int off = 128; off > 0; off >>= 1) {
        if (tid < off) sb[tid] += sb[tid + off];
        __syncthreads();
    }
    if (tid == 0) {
        const int li = *(const int*)lamp;
        const float lam = (li >= -1000000 && li <= 1000000)
                            ? (float)li : *(const float*)lamp;
        float fm = 0.f;
        for (int i = 0; i < Bf; ++i) fm += fbpp[i];
        fm /= (float)Bf;
        out[0] = sb[0] + lam * fm;
    }
}

extern "C" void kernel_launch(void* const* d_in, const int* in_sizes, int n_in,
                              void* d_out, int out_size, void* d_ws, size_t ws_size,
                              hipStream_t stream) {
    const float* pred = (const float*)d_in[0];
    const float* targ = (const float*)d_in[1];
    const float* fbpp = (const float*)d_in[2];
    const void*  lamp = d_in[3];

    const int B = in_sizes[2];
    const int N = in_sizes[0] / (3 * B);
    const int M = in_sizes[1] / (3 * B);
    const int NpadP = roundup_h(N, RPB);
    const int NpadT = roundup_h(M, RPB);
    const int NpadMax = (NpadP > NpadT) ? NpadP : NpadT;

    // ---- workspace layout (+8KB slack after each pack for prefetch OOB) ----
    size_t o = 0;
    auto take = [&](size_t bytes) {
        size_t r = o; o += (bytes + 255) & ~(size_t)255; return r;
    };
    unsigned short* aP = (unsigned short*)((char*)d_ws +
                         take((size_t)B * NpadP * 32 + 8192));
    unsigned short* bP = (unsigned short*)((char*)d_ws +
                         take((size_t)B * NpadP * 32 + 8192));
    unsigned short* aT = (unsigned short*)((char*)d_ws +
                         take((size_t)B * NpadT * 32 + 8192));
    unsigned short* bT = (unsigned short*)((char*)d_ws +
                         take((size_t)B * NpadT * 32 + 8192));
    float* rowpart = (float*)((char*)d_ws +
                     take((size_t)2 * B * YS * NpadMax * sizeof(float)));
    float* partial = (float*)((char*)d_ws + take(256 * sizeof(float)));
    (void)ws_size;

    // ---- 1) pack both clouds into A/B MFMA K-patterns ----
    pack_kernel<<<(B * NpadMax + 255) / 256, 256, 0, stream>>>(
        pred, targ, B, N, M, NpadP, NpadT, aP, bP, aT, bT);

    // ---- 2) MFMA pair sweep (both directions) ----
    const int SP = NpadMax / RPB;
    const int blocks = 2 * B * YS * SP;
    mfma_sweep<<<blocks, 256, 0, stream>>>(
        aP, bP, aT, bT, B, N, M, NpadP, NpadT, NpadMax, rowpart);

    // ---- 3) combine splits + clamp + weighted sum ----
    combine_kernel<<<256, 256, 0, stream>>>(
        rowpart, B, N, M, NpadP, NpadT, NpadMax,
        1.f / ((float)B * (float)N), 1.f / ((float)B * (float)M), partial);

    // ---- 4) finalize ----
    finalize_kernel<<<1, 256, 0, stream>>>(partial, 256, fbpp, B, lamp,
                                           (float*)d_out);
}